// Round 1
// baseline (838.801 us; speedup 1.0000x reference)
//
#include <hip/hip_runtime.h>
#include <hip/hip_bf16.h>
#include <cstdint>
#include <cstddef>

#define L_LAYERS 3
#define H_HEADS 8
#define D_EMB 128
#define DKV 16
#define FF_DIM 512
#define B_BATCH 32
#define N_SEQ 512
#define F_INP 16
#define OUT_DIM 3
#define M_ROWS (B_BATCH * N_SEQ)   // 16384
#define ATT_SCALE 0.25f            // 1/sqrt(16)

// ---------------- mask bit-pack: one bit per mask element via ballot ----------------
__global__ __launch_bounds__(256) void pack_mask_kernel(const int* __restrict__ mask,
                                                        unsigned long long* __restrict__ pm) {
    int gid = blockIdx.x * 256 + threadIdx.x;       // grid sized exactly B*N*N/256
    int v = mask[gid];
    unsigned long long bal = __ballot(v != 0);
    if ((threadIdx.x & 63) == 0) pm[gid >> 6] = bal;
}

// -------- repack Wq/Wk/Wv [L,H,D,DK] -> [L][D][proj*128 + h*16 + k] (GEMM B-matrix) --------
__global__ __launch_bounds__(256) void repack_qkv_kernel(const float* __restrict__ Wq,
                                                         const float* __restrict__ Wk,
                                                         const float* __restrict__ Wv,
                                                         float* __restrict__ dst) {
    int idx = blockIdx.x * 256 + threadIdx.x;       // total 3*128*384 = 147456
    if (idx >= L_LAYERS * D_EMB * 384) return;
    int col = idx % 384;
    int d   = (idx / 384) % D_EMB;
    int l   = idx / (384 * D_EMB);
    int proj = col >> 7;
    int hh   = (col & 127) >> 4;
    int k    = col & 15;
    const float* src = (proj == 0) ? Wq : (proj == 1) ? Wk : Wv;
    dst[idx] = src[((size_t)(l * H_HEADS + hh) * D_EMB + d) * DKV + k];
}

// ---------------- generic tiled fp32 GEMM: C = [relu]( A@B [+bias] [+Cin] ) ----------------
// A [M,K] rm, B [K,N] rm, C [M,N] rm. BM=BN=64, BK=16, 256 threads, 4x4 micro-tile.
template <bool RELU, bool BIAS, bool RES>
__global__ __launch_bounds__(256) void gemm_kernel(const float* __restrict__ A,
                                                   const float* __restrict__ Bm,
                                                   const float* __restrict__ bias,
                                                   const float* __restrict__ Cin,
                                                   float* __restrict__ C,
                                                   int M, int N, int K) {
    __shared__ float As[64][17];   // +1 pad: conflict-free scalar reads across ty
    __shared__ float Bs[16][64];
    const int tid = threadIdx.x;
    const int tx = tid & 15, ty = tid >> 4;
    const int m0 = blockIdx.y * 64, n0 = blockIdx.x * 64;
    const int ar = tid >> 2, ac = (tid & 3) << 2;   // A tile load: 64 rows x 16 cols
    const int brr = tid >> 4, bc = (tid & 15) << 2; // B tile load: 16 rows x 64 cols

    float acc[4][4];
#pragma unroll
    for (int i = 0; i < 4; i++)
#pragma unroll
        for (int j = 0; j < 4; j++) acc[i][j] = 0.f;

    for (int k0 = 0; k0 < K; k0 += 16) {
        float4 av = *(const float4*)&A[(size_t)(m0 + ar) * K + k0 + ac];
        float4 bv = *(const float4*)&Bm[(size_t)(k0 + brr) * N + n0 + bc];
        As[ar][ac + 0] = av.x; As[ar][ac + 1] = av.y;
        As[ar][ac + 2] = av.z; As[ar][ac + 3] = av.w;
        *(float4*)&Bs[brr][bc] = bv;
        __syncthreads();
#pragma unroll
        for (int kk = 0; kk < 16; kk++) {
            float a_[4];
#pragma unroll
            for (int i = 0; i < 4; i++) a_[i] = As[ty * 4 + i][kk];
            float4 b4 = *(float4*)&Bs[kk][tx << 2];
            float b_[4] = {b4.x, b4.y, b4.z, b4.w};
#pragma unroll
            for (int i = 0; i < 4; i++)
#pragma unroll
                for (int j = 0; j < 4; j++) acc[i][j] += a_[i] * b_[j];
        }
        __syncthreads();
    }

    const int n = n0 + (tx << 2);
    float bvals[4] = {0.f, 0.f, 0.f, 0.f};
    if (BIAS) {
        bvals[0] = bias[n + 0]; bvals[1] = bias[n + 1];
        bvals[2] = bias[n + 2]; bvals[3] = bias[n + 3];
    }
#pragma unroll
    for (int i = 0; i < 4; i++) {
        const int m = m0 + ty * 4 + i;
        float r[4];
#pragma unroll
        for (int j = 0; j < 4; j++) r[j] = acc[i][j] + bvals[j];
        if (RES) {
            float4 cv = *(const float4*)&Cin[(size_t)m * N + n];
            r[0] += cv.x; r[1] += cv.y; r[2] += cv.z; r[3] += cv.w;
        }
        if (RELU) {
#pragma unroll
            for (int j = 0; j < 4; j++) r[j] = fmaxf(r[j], 0.f);
        }
        float4 o; o.x = r[0]; o.y = r[1]; o.z = r[2]; o.w = r[3];
        *(float4*)&C[(size_t)m * N + n] = o;
    }
}

// ---------------- attention: block = (head,b), 512 threads = 1 query each ----------------
// QKV rm [16384, 384] cols: q=h*16+k, k=128+h*16+k, v=256+h*16+k. Online softmax.
__global__ __launch_bounds__(512) void attn_kernel(const float* __restrict__ QKV,
                                                   const unsigned int* __restrict__ pm,
                                                   float* __restrict__ Aout) {
    __shared__ float Ks[N_SEQ * 16];
    __shared__ float Vs[N_SEQ * 16];
    const int h = blockIdx.x & 7;
    const int b = blockIdx.x >> 3;
    const int t = threadIdx.x;
    const size_t rowbase = (size_t)(b * N_SEQ + t) * 384;

    const float4* kg = (const float4*)(QKV + rowbase + 128 + h * 16);
    const float4* vg = (const float4*)(QKV + rowbase + 256 + h * 16);
    float4* ks4 = (float4*)(Ks + t * 16);
    float4* vs4 = (float4*)(Vs + t * 16);
#pragma unroll
    for (int i = 0; i < 4; i++) ks4[i] = kg[i];
#pragma unroll
    for (int i = 0; i < 4; i++) vs4[i] = vg[i];

    const float4* qg = (const float4*)(QKV + rowbase + h * 16);
    float q[16];
#pragma unroll
    for (int i = 0; i < 4; i++) {
        float4 qv = qg[i];
        q[i * 4 + 0] = qv.x * ATT_SCALE; q[i * 4 + 1] = qv.y * ATT_SCALE;
        q[i * 4 + 2] = qv.z * ATT_SCALE; q[i * 4 + 3] = qv.w * ATT_SCALE;
    }
    __syncthreads();

    float mrun = -1e30f, lrun = 0.f;
    float acc[16];
#pragma unroll
    for (int i = 0; i < 16; i++) acc[i] = 0.f;

    const unsigned int* pmrow = pm + ((size_t)(b * N_SEQ + t) << 4);
    for (int w = 0; w < 16; w++) {
        unsigned int bits = pmrow[w];
#pragma unroll 4
        for (int j = 0; j < 32; j++) {
            const int n = (w << 5) + j;
            const float4* kr = (const float4*)(Ks + n * 16);
            float s = 0.f;
#pragma unroll
            for (int i = 0; i < 4; i++) {
                float4 kk = kr[i];
                s += q[i * 4 + 0] * kk.x + q[i * 4 + 1] * kk.y
                   + q[i * 4 + 2] * kk.z + q[i * 4 + 3] * kk.w;
            }
            const bool mb = (bits >> j) & 1u;
            const float sv = mb ? s : -1e30f;
            const float mnew = fmaxf(mrun, sv);
            const float alpha = __expf(mrun - mnew);
            const float p = mb ? __expf(s - mnew) : 0.f;
            lrun = lrun * alpha + p;
            const float4* vr = (const float4*)(Vs + n * 16);
#pragma unroll
            for (int i = 0; i < 4; i++) {
                float4 vv = vr[i];
                acc[i * 4 + 0] = acc[i * 4 + 0] * alpha + p * vv.x;
                acc[i * 4 + 1] = acc[i * 4 + 1] * alpha + p * vv.y;
                acc[i * 4 + 2] = acc[i * 4 + 2] * alpha + p * vv.z;
                acc[i * 4 + 3] = acc[i * 4 + 3] * alpha + p * vv.w;
            }
            mrun = mnew;
        }
    }
    const float inv = 1.f / lrun;
    float4* og = (float4*)(Aout + (size_t)(b * N_SEQ + t) * 128 + h * 16);
#pragma unroll
    for (int i = 0; i < 4; i++) {
        float4 o;
        o.x = acc[i * 4 + 0] * inv; o.y = acc[i * 4 + 1] * inv;
        o.z = acc[i * 4 + 2] * inv; o.w = acc[i * 4 + 3] * inv;
        og[i] = o;
    }
}

// ------------- pooled readout part: pb[b][o] = br[o] + relu(mean_n(h) @ Wp) @ Wr[:128] -------------
__global__ __launch_bounds__(128) void pool_kernel(const float* __restrict__ h,
                                                   const float* __restrict__ Wp,
                                                   const float* __restrict__ Wr,
                                                   const float* __restrict__ br,
                                                   float* __restrict__ pb) {
    const int b = blockIdx.x, t = threadIdx.x;
    __shared__ float pooled[128];
    __shared__ float rp[128];
    float acc = 0.f;
    const float* hb = h + (size_t)b * N_SEQ * D_EMB;
    for (int n = 0; n < N_SEQ; n++) acc += hb[n * D_EMB + t];
    pooled[t] = acc * (1.0f / N_SEQ);
    __syncthreads();
    float acc2 = 0.f;
    for (int d = 0; d < D_EMB; d++) acc2 += pooled[d] * Wp[d * D_EMB + t];
    rp[t] = fmaxf(acc2, 0.f);
    __syncthreads();
    if (t < OUT_DIM) {
        float a = br[t];
        for (int j = 0; j < D_EMB; j++) a += rp[j] * Wr[j * OUT_DIM + t];
        pb[b * OUT_DIM + t] = a;
    }
}

// ------------- final: out[bn][o] = pb[b][o] + relu(h[bn]) @ Wr[128:256] -------------
__global__ __launch_bounds__(128) void out_kernel(const float* __restrict__ h,
                                                  const float* __restrict__ Wr,
                                                  const float* __restrict__ pb,
                                                  float* __restrict__ out) {
    const int row = blockIdx.x, tid = threadIdx.x;
    __shared__ float rp[128];
    rp[tid] = fmaxf(h[(size_t)row * D_EMB + tid], 0.f);
    __syncthreads();
    if (tid < 96) {
        const int o = tid >> 5, j0 = tid & 31;
        float acc = 0.f;
        for (int j = j0; j < 128; j += 32) acc += rp[j] * Wr[(128 + j) * OUT_DIM + o];
        for (int off = 16; off; off >>= 1) acc += __shfl_down(acc, off, 32);
        if (j0 == 0) out[(size_t)row * OUT_DIM + o] = acc + pb[(row >> 9) * OUT_DIM + o];
    }
}

extern "C" void kernel_launch(void* const* d_in, const int* in_sizes, int n_in,
                              void* d_out, int out_size, void* d_ws, size_t ws_size,
                              hipStream_t stream) {
    const float* x    = (const float*)d_in[0];
    const int*   mask = (const int*)d_in[1];
    const float* We   = (const float*)d_in[2];
    const float* Wq   = (const float*)d_in[3];
    const float* Wk   = (const float*)d_in[4];
    const float* Wv   = (const float*)d_in[5];
    const float* Wout = (const float*)d_in[6];
    const float* Wff1 = (const float*)d_in[7];
    const float* bff1 = (const float*)d_in[8];
    const float* Wff2 = (const float*)d_in[9];
    const float* bff2 = (const float*)d_in[10];
    const float* Wp   = (const float*)d_in[11];
    const float* Wr   = (const float*)d_in[12];
    const float* br   = (const float*)d_in[13];
    float* out = (float*)d_out;

    char* ws = (char*)d_ws;
    unsigned long long* pm64 = (unsigned long long*)(ws + 0);            // 1 MiB
    const unsigned int* pm32 = (const unsigned int*)(ws + 0);
    float* wqkv = (float*)(ws + 1048576);                                // 576 KiB
    float* hbuf = (float*)(ws + 1638400);                                // 8 MiB
    float* qkvbuf = (float*)(ws + 10027008);                             // 32 MiB (QKV / FFN-t aliased)
    float* tbuf = qkvbuf;
    float* abuf = (float*)(ws + 43581440);                               // 8 MiB
    float* pbbuf = (float*)(ws + 51970048);                              // 384 B

    // one-time-per-call preprocessing (idempotent, same work every call)
    pack_mask_kernel<<<(B_BATCH * N_SEQ * N_SEQ) / 256, 256, 0, stream>>>(mask, pm64);
    repack_qkv_kernel<<<576, 256, 0, stream>>>(Wq, Wk, Wv, wqkv);

    // embed: h = relu(x @ We)   [16384,16]@[16,128]
    gemm_kernel<true, false, false><<<dim3(128 / 64, M_ROWS / 64), 256, 0, stream>>>(
        x, We, nullptr, nullptr, hbuf, M_ROWS, 128, 16);

    for (int l = 0; l < L_LAYERS; l++) {
        // QKV: [16384,128]@[128,384]
        gemm_kernel<false, false, false><<<dim3(384 / 64, M_ROWS / 64), 256, 0, stream>>>(
            hbuf, wqkv + (size_t)l * D_EMB * 384, nullptr, nullptr, qkvbuf, M_ROWS, 384, 128);
        // attention per (h,b)
        attn_kernel<<<H_HEADS * B_BATCH, 512, 0, stream>>>(qkvbuf, pm32, abuf);
        // h += A @ Wout  ([H,DK,D] is already [128,128] row-major with row = h*16+k)
        gemm_kernel<false, false, true><<<dim3(128 / 64, M_ROWS / 64), 256, 0, stream>>>(
            abuf, Wout + (size_t)l * 128 * 128, nullptr, hbuf, hbuf, M_ROWS, 128, 128);
        // t = relu(h @ Wff1 + bff1)
        gemm_kernel<true, true, false><<<dim3(512 / 64, M_ROWS / 64), 256, 0, stream>>>(
            hbuf, Wff1 + (size_t)l * 128 * 512, bff1 + l * 512, nullptr, tbuf, M_ROWS, 512, 128);
        // h += t @ Wff2 + bff2
        gemm_kernel<false, true, true><<<dim3(128 / 64, M_ROWS / 64), 256, 0, stream>>>(
            tbuf, Wff2 + (size_t)l * 512 * 128, bff2 + l * 128, hbuf, hbuf, M_ROWS, 128, 512);
    }

    pool_kernel<<<B_BATCH, 128, 0, stream>>>(hbuf, Wp, Wr, br, pbbuf);
    out_kernel<<<M_ROWS, 128, 0, stream>>>(hbuf, Wr, pbbuf, out);
}

// Round 2
// 750.788 us; speedup vs baseline: 1.1172x; 1.1172x over previous
//
#include <hip/hip_runtime.h>
#include <cstdint>
#include <cstddef>

#define L_LAYERS 3
#define H_HEADS 8
#define D_EMB 128
#define DKV 16
#define FF_DIM 512
#define B_BATCH 32
#define N_SEQ 512
#define F_INP 16
#define OUT_DIM 3
#define M_ROWS (B_BATCH * N_SEQ)   // 16384
#define ATT_SCALE 0.25f            // 1/sqrt(16)

typedef unsigned short ushort_t;
typedef unsigned int uint_t;
typedef __attribute__((ext_vector_type(8))) short short8;
typedef __attribute__((ext_vector_type(4))) float f32x4;

__device__ inline ushort_t f2bf(float x) {   // RNE float->bf16
    union { float f; uint_t u; } v; v.f = x;
    uint_t r = v.u + 0x7fffu + ((v.u >> 16) & 1u);
    return (ushort_t)(r >> 16);
}

__device__ inline void gload16(const void* g, void* l) {
    __builtin_amdgcn_global_load_lds(
        (const __attribute__((address_space(1))) unsigned int*)g,
        (__attribute__((address_space(3))) unsigned int*)l, 16, 0, 0);
}

// ---------------- mask bit-pack ----------------
__global__ __launch_bounds__(256) void pack_mask_kernel(const int* __restrict__ mask,
                                                        unsigned long long* __restrict__ pm) {
    int gid = blockIdx.x * 256 + threadIdx.x;
    int v = mask[gid];
    unsigned long long bal = __ballot(v != 0);
    if ((threadIdx.x & 63) == 0) pm[gid >> 6] = bal;
}

// -------- Wq/Wk/Wv [L,H,D,DK] -> bf16 B^T layout [L][n=proj*128+h*16+k][d] --------
__global__ __launch_bounds__(256) void repack_qkv_bt_kernel(const float* __restrict__ Wq,
                                                            const float* __restrict__ Wk,
                                                            const float* __restrict__ Wv,
                                                            ushort_t* __restrict__ dst) {
    int idx = blockIdx.x * 256 + threadIdx.x;   // exactly L*384*128
    int d = idx & 127;
    int n = (idx >> 7) % 384;
    int l = idx / (384 * 128);
    int proj = n >> 7, hh = (n & 127) >> 4, kk = n & 15;
    const float* src = proj == 0 ? Wq : proj == 1 ? Wk : Wv;
    dst[idx] = f2bf(src[((size_t)(l * 8 + hh) * 128 + d) * 16 + kk]);
}

// -------- generic batched transpose to bf16: dst[b][c][r] = src[b][r][c] --------
__global__ __launch_bounds__(256) void tr_bf16_kernel(const float* __restrict__ src,
                                                      ushort_t* __restrict__ dst,
                                                      int R, int C, int total) {
    int idx = blockIdx.x * 256 + threadIdx.x;
    if (idx >= total) return;
    int b = idx / (R * C);
    int rem = idx - b * (R * C);
    int r = rem / C, c = rem - r * C;
    dst[(size_t)b * R * C + (size_t)c * R + r] = f2bf(src[idx]);
}

// ---------------- embed: h = relu(x @ We), write fp32 + bf16 ----------------
__global__ __launch_bounds__(256) void embed_kernel(const float* __restrict__ x,
                                                    const float* __restrict__ We,
                                                    float* __restrict__ hf,
                                                    ushort_t* __restrict__ hb) {
    const int t = threadIdx.x;
    const int d = t & 127;
    const int m = blockIdx.x * 2 + (t >> 7);
    const float* xr = x + (size_t)m * 16;
    float acc = 0.f;
#pragma unroll
    for (int k = 0; k < 16; k++) acc += xr[k] * We[k * 128 + d];
    acc = fmaxf(acc, 0.f);
    hf[(size_t)m * 128 + d] = acc;
    hb[(size_t)m * 128 + d] = f2bf(acc);
}

// ---------------- bf16 MFMA GEMM (m97-style): C = [relu](A @ Bt^T [+bias] [+Cin]) ----------------
// A [M,K] bf16 rm, Bt [N,K] bf16 rm ("B transposed"), BK=32, BN=128, BM in {64,128}.
// 256 threads = 4 waves. BM=128: wave grid 2x2 (64x64 each, 4x4 MFMA subtiles).
// BM=64: waves side by side in N (64x32 each, 4x2 subtiles).
template <int BM, bool RELU, bool BIAS, bool RES, bool WF32, bool WB16>
__global__ __launch_bounds__(256) void gemm_bt(const ushort_t* __restrict__ A,
                                               const ushort_t* __restrict__ Bt,
                                               const float* __restrict__ bias,
                                               const float* __restrict__ Cin,
                                               float* __restrict__ Cf,
                                               ushort_t* __restrict__ Cb,
                                               int M, int N, int K) {
    constexpr int NJ = (BM == 128) ? 4 : 2;
    __shared__ __align__(16) ushort_t Asm[BM * 32];
    __shared__ __align__(16) ushort_t Bsm[128 * 32];
    const int tid = threadIdx.x;
    const int w = tid >> 6, l = tid & 63;
    const int m0 = blockIdx.y * BM, n0 = blockIdx.x * 128;
    const int WM = (BM == 128) ? (w & 1) * 64 : 0;
    const int WN = (BM == 128) ? (w >> 1) * 64 : w * 32;
    const int lr = l & 15, lq = l >> 4;
    const int sar = w * 16 + (l >> 2);     // staging row (+ it*64)
    const int sac = (l & 3) * 8;           // staging col (bf16 elems)

    f32x4 acc[4][NJ];
#pragma unroll
    for (int i = 0; i < 4; i++)
#pragma unroll
        for (int j = 0; j < NJ; j++) acc[i][j] = (f32x4){0.f, 0.f, 0.f, 0.f};

    for (int k0 = 0; k0 < K; k0 += 32) {
#pragma unroll
        for (int it = 0; it < BM / 64; it++)
            gload16(A + (size_t)(m0 + it * 64 + sar) * K + k0 + sac,
                    &Asm[(it * 64 + sar) * 32 + sac]);
#pragma unroll
        for (int it = 0; it < 2; it++)
            gload16(Bt + (size_t)(n0 + it * 64 + sar) * K + k0 + sac,
                    &Bsm[(it * 64 + sar) * 32 + sac]);
        __syncthreads();
        short8 af[4], bfr[NJ];
#pragma unroll
        for (int i = 0; i < 4; i++)
            af[i] = *(const short8*)&Asm[(WM + i * 16 + lr) * 32 + lq * 8];
#pragma unroll
        for (int j = 0; j < NJ; j++)
            bfr[j] = *(const short8*)&Bsm[(WN + j * 16 + lr) * 32 + lq * 8];
#pragma unroll
        for (int i = 0; i < 4; i++)
#pragma unroll
            for (int j = 0; j < NJ; j++)
                acc[i][j] = __builtin_amdgcn_mfma_f32_16x16x32_bf16(af[i], bfr[j], acc[i][j], 0, 0, 0);
        __syncthreads();
    }

    float bv[NJ];
#pragma unroll
    for (int j = 0; j < NJ; j++) {
        const int n = n0 + WN + j * 16 + lr;
        bv[j] = BIAS ? bias[n] : 0.f;
    }
#pragma unroll
    for (int i = 0; i < 4; i++) {
#pragma unroll
        for (int r = 0; r < 4; r++) {
            const int m = m0 + WM + i * 16 + lq * 4 + r;
#pragma unroll
            for (int j = 0; j < NJ; j++) {
                const int n = n0 + WN + j * 16 + lr;
                float v = acc[i][j][r] + bv[j];
                if (RES) v += Cin[(size_t)m * N + n];
                if (RELU) v = fmaxf(v, 0.f);
                if (WF32) Cf[(size_t)m * N + n] = v;
                if (WB16) Cb[(size_t)m * N + n] = f2bf(v);
            }
        }
    }
}

// ---------------- attention: block=(h,b), 512 thr = 1 query each, chunk-32 deferred rescale ----------------
__global__ __launch_bounds__(512) void attn_kernel(const float* __restrict__ QKV,
                                                   const uint_t* __restrict__ pm,
                                                   ushort_t* __restrict__ Aout) {
    __shared__ float Ks[N_SEQ * 16];
    __shared__ float Vs[N_SEQ * 16];
    const int h = blockIdx.x & 7;
    const int b = blockIdx.x >> 3;
    const int t = threadIdx.x;
    const size_t rowbase = (size_t)(b * N_SEQ + t) * 384;

    {
        const float4* kg = (const float4*)(QKV + rowbase + 128 + h * 16);
        const float4* vg = (const float4*)(QKV + rowbase + 256 + h * 16);
        float4* ks4 = (float4*)(Ks + t * 16);
        float4* vs4 = (float4*)(Vs + t * 16);
#pragma unroll
        for (int i = 0; i < 4; i++) ks4[i] = kg[i];
#pragma unroll
        for (int i = 0; i < 4; i++) vs4[i] = vg[i];
    }
    const float4* qg = (const float4*)(QKV + rowbase + h * 16);
    float q[16];
#pragma unroll
    for (int i = 0; i < 4; i++) {
        float4 qv = qg[i];
        q[i * 4 + 0] = qv.x * ATT_SCALE; q[i * 4 + 1] = qv.y * ATT_SCALE;
        q[i * 4 + 2] = qv.z * ATT_SCALE; q[i * 4 + 3] = qv.w * ATT_SCALE;
    }
    __syncthreads();

    float mrun = -1e30f, lrun = 0.f;
    float acc[16];
#pragma unroll
    for (int i = 0; i < 16; i++) acc[i] = 0.f;

    const uint_t* pmrow = pm + ((size_t)(b * N_SEQ + t) << 4);
    for (int w = 0; w < 16; w++) {
        const uint_t bits = pmrow[w];
        float s[32];
#pragma unroll 8
        for (int j = 0; j < 32; j++) {
            const float4* kr = (const float4*)(Ks + ((w << 5) + j) * 16);
            float d0 = 0.f;
#pragma unroll
            for (int i = 0; i < 4; i++) {
                float4 kk = kr[i];
                d0 += q[i * 4 + 0] * kk.x + q[i * 4 + 1] * kk.y
                    + q[i * 4 + 2] * kk.z + q[i * 4 + 3] * kk.w;
            }
            s[j] = ((bits >> j) & 1u) ? d0 : -1e30f;
        }
        float cmax = -1e30f;
#pragma unroll
        for (int j = 0; j < 32; j++) cmax = fmaxf(cmax, s[j]);
        const float mnew = fmaxf(mrun, cmax);
        const float alpha = __expf(mrun - mnew);
        lrun *= alpha;
#pragma unroll
        for (int i = 0; i < 16; i++) acc[i] *= alpha;
#pragma unroll 8
        for (int j = 0; j < 32; j++) {
            const float p = ((bits >> j) & 1u) ? __expf(s[j] - mnew) : 0.f;
            lrun += p;
            const float4* vr = (const float4*)(Vs + ((w << 5) + j) * 16);
#pragma unroll
            for (int i = 0; i < 4; i++) {
                float4 vv = vr[i];
                acc[i * 4 + 0] += p * vv.x;
                acc[i * 4 + 1] += p * vv.y;
                acc[i * 4 + 2] += p * vv.z;
                acc[i * 4 + 3] += p * vv.w;
            }
        }
        mrun = mnew;
    }
    const float inv = 1.f / lrun;
    uint_t o[8];
#pragma unroll
    for (int i = 0; i < 8; i++)
        o[i] = (uint_t)f2bf(acc[2 * i] * inv) | ((uint_t)f2bf(acc[2 * i + 1] * inv) << 16);
    uint4* og = (uint4*)(Aout + (size_t)(b * N_SEQ + t) * 128 + h * 16);
    og[0] = make_uint4(o[0], o[1], o[2], o[3]);
    og[1] = make_uint4(o[4], o[5], o[6], o[7]);
}

// ------------- pooled readout part -------------
__global__ __launch_bounds__(128) void pool_kernel(const float* __restrict__ h,
                                                   const float* __restrict__ Wp,
                                                   const float* __restrict__ Wr,
                                                   const float* __restrict__ br,
                                                   float* __restrict__ pb) {
    const int b = blockIdx.x, t = threadIdx.x;
    __shared__ float pooled[128];
    __shared__ float rp[128];
    float acc = 0.f;
    const float* hb = h + (size_t)b * N_SEQ * D_EMB;
    for (int n = 0; n < N_SEQ; n++) acc += hb[n * D_EMB + t];
    pooled[t] = acc * (1.0f / N_SEQ);
    __syncthreads();
    float acc2 = 0.f;
    for (int d = 0; d < D_EMB; d++) acc2 += pooled[d] * Wp[d * D_EMB + t];
    rp[t] = fmaxf(acc2, 0.f);
    __syncthreads();
    if (t < OUT_DIM) {
        float a = br[t];
        for (int j = 0; j < D_EMB; j++) a += rp[j] * Wr[j * OUT_DIM + t];
        pb[b * OUT_DIM + t] = a;
    }
}

// ------------- final readout -------------
__global__ __launch_bounds__(128) void out_kernel(const float* __restrict__ h,
                                                  const float* __restrict__ Wr,
                                                  const float* __restrict__ pb,
                                                  float* __restrict__ out) {
    const int row = blockIdx.x, tid = threadIdx.x;
    __shared__ float rp[128];
    rp[tid] = fmaxf(h[(size_t)row * D_EMB + tid], 0.f);
    __syncthreads();
    if (tid < 96) {
        const int o = tid >> 5, j0 = tid & 31;
        float acc = 0.f;
        for (int j = j0; j < 128; j += 32) acc += rp[j] * Wr[(128 + j) * OUT_DIM + o];
        for (int off = 16; off; off >>= 1) acc += __shfl_down(acc, off, 32);
        if (j0 == 0) out[(size_t)row * OUT_DIM + o] = acc + pb[(row >> 9) * OUT_DIM + o];
    }
}

extern "C" void kernel_launch(void* const* d_in, const int* in_sizes, int n_in,
                              void* d_out, int out_size, void* d_ws, size_t ws_size,
                              hipStream_t stream) {
    const float* x    = (const float*)d_in[0];
    const int*   mask = (const int*)d_in[1];
    const float* We   = (const float*)d_in[2];
    const float* Wq   = (const float*)d_in[3];
    const float* Wk   = (const float*)d_in[4];
    const float* Wv   = (const float*)d_in[5];
    const float* Wout = (const float*)d_in[6];
    const float* Wff1 = (const float*)d_in[7];
    const float* bff1 = (const float*)d_in[8];
    const float* Wff2 = (const float*)d_in[9];
    const float* bff2 = (const float*)d_in[10];
    const float* Wp   = (const float*)d_in[11];
    const float* Wr   = (const float*)d_in[12];
    const float* br   = (const float*)d_in[13];
    float* out = (float*)d_out;

    char* ws = (char*)d_ws;
    unsigned long long* pm64 = (unsigned long long*)(ws + 0);        // 1 MiB
    const uint_t* pm32       = (const uint_t*)(ws + 0);
    ushort_t* wqkvT = (ushort_t*)(ws + 1048576);                     // 288 KiB  (3*384*128)
    ushort_t* woutT = (ushort_t*)(ws + 1343488);                     // 96 KiB   (3*128*128)
    ushort_t* wff1T = (ushort_t*)(ws + 1441792);                     // 384 KiB  (3*512*128)
    ushort_t* wff2T = (ushort_t*)(ws + 1835008);                     // 384 KiB  (3*128*512)
    float*    pbbuf = (float*)(ws + 2228224);                        // 384 B
    float*    hbuf  = (float*)(ws + 4194304);                        // 8 MiB fp32 residual
    ushort_t* hb16  = (ushort_t*)(ws + 12582912);                    // 4 MiB bf16 mirror of h
    float*    qkv   = (float*)(ws + 16777216);                       // 24 MiB fp32 QKV
    ushort_t* t16   = (ushort_t*)(ws + 16777216);                    // 16 MiB bf16 FFN mid (aliases qkv)
    ushort_t* a16   = (ushort_t*)(ws + 41943040);                    // 4 MiB bf16 attn out

    // per-call preprocessing (idempotent)
    pack_mask_kernel<<<(B_BATCH * N_SEQ * N_SEQ) / 256, 256, 0, stream>>>(mask, pm64);
    repack_qkv_bt_kernel<<<576, 256, 0, stream>>>(Wq, Wk, Wv, wqkvT);
    tr_bf16_kernel<<<192, 256, 0, stream>>>(Wout, woutT, 128, 128, 3 * 128 * 128);
    tr_bf16_kernel<<<768, 256, 0, stream>>>(Wff1, wff1T, 128, 512, 3 * 128 * 512);
    tr_bf16_kernel<<<768, 256, 0, stream>>>(Wff2, wff2T, 512, 128, 3 * 512 * 128);

    embed_kernel<<<M_ROWS / 2, 256, 0, stream>>>(x, We, hbuf, hb16);

    for (int l = 0; l < L_LAYERS; l++) {
        // QKV: [16384,128]bf16 @ [128,384] -> qkv fp32
        gemm_bt<128, false, false, false, true, false><<<dim3(3, M_ROWS / 128), 256, 0, stream>>>(
            hb16, wqkvT + (size_t)l * 384 * 128, nullptr, nullptr, qkv, nullptr,
            M_ROWS, 384, 128);
        // attention -> a16 bf16
        attn_kernel<<<H_HEADS * B_BATCH, 512, 0, stream>>>(qkv, pm32, a16);
        // h += a16 @ Wout  (write hbuf fp32 + hb16)
        gemm_bt<64, false, false, true, true, true><<<dim3(1, M_ROWS / 64), 256, 0, stream>>>(
            a16, woutT + (size_t)l * 128 * 128, nullptr, hbuf, hbuf, hb16,
            M_ROWS, 128, 128);
        // t = relu(h @ Wff1 + bff1) -> t16 bf16 only
        gemm_bt<128, true, true, false, false, true><<<dim3(4, M_ROWS / 128), 256, 0, stream>>>(
            hb16, wff1T + (size_t)l * 512 * 128, bff1 + l * 512, nullptr, nullptr, t16,
            M_ROWS, 512, 128);
        // h += t16 @ Wff2 + bff2  (write hbuf fp32 + hb16)
        gemm_bt<64, false, true, true, true, true><<<dim3(1, M_ROWS / 64), 256, 0, stream>>>(
            t16, wff2T + (size_t)l * 128 * 512, bff2 + l * 128, hbuf, hbuf, hb16,
            M_ROWS, 128, 512);
    }

    pool_kernel<<<B_BATCH, 128, 0, stream>>>(hbuf, Wp, Wr, br, pbbuf);
    out_kernel<<<M_ROWS, 128, 0, stream>>>(hbuf, Wr, pbbuf, out);
}

// Round 3
// 437.290 us; speedup vs baseline: 1.9182x; 1.7169x over previous
//
#include <hip/hip_runtime.h>
#include <cstdint>
#include <cstddef>

#define L_LAYERS 3
#define H_HEADS 8
#define D_EMB 128
#define DKV 16
#define FF_DIM 512
#define B_BATCH 32
#define N_SEQ 512
#define F_INP 16
#define OUT_DIM 3
#define M_ROWS (B_BATCH * N_SEQ)   // 16384

typedef unsigned short ushort_t;
typedef unsigned int uint_t;
typedef __attribute__((ext_vector_type(8))) short short8;
typedef __attribute__((ext_vector_type(4))) float f32x4;

__device__ inline ushort_t f2bf(float x) {   // RNE float->bf16
    union { float f; uint_t u; } v; v.f = x;
    uint_t r = v.u + 0x7fffu + ((v.u >> 16) & 1u);
    return (ushort_t)(r >> 16);
}

__device__ inline void gload16(const void* g, void* l) {
    __builtin_amdgcn_global_load_lds(
        (const __attribute__((address_space(1))) unsigned int*)g,
        (__attribute__((address_space(3))) unsigned int*)l, 16, 0, 0);
}

// ---------------- mask bit-pack ----------------
__global__ __launch_bounds__(256) void pack_mask_kernel(const int* __restrict__ mask,
                                                        unsigned long long* __restrict__ pm) {
    int gid = blockIdx.x * 256 + threadIdx.x;
    int v = mask[gid];
    unsigned long long bal = __ballot(v != 0);
    if ((threadIdx.x & 63) == 0) pm[gid >> 6] = bal;
}

// -------- Wq/Wk/Wv [L,H,D,DK] -> bf16 B^T layout [L][n=proj*128+h*16+k][d] --------
__global__ __launch_bounds__(256) void repack_qkv_bt_kernel(const float* __restrict__ Wq,
                                                            const float* __restrict__ Wk,
                                                            const float* __restrict__ Wv,
                                                            ushort_t* __restrict__ dst) {
    int idx = blockIdx.x * 256 + threadIdx.x;   // exactly L*384*128
    int d = idx & 127;
    int n = (idx >> 7) % 384;
    int l = idx / (384 * 128);
    int proj = n >> 7, hh = (n & 127) >> 4, kk = n & 15;
    const float* src = proj == 0 ? Wq : proj == 1 ? Wk : Wv;
    dst[idx] = f2bf(src[((size_t)(l * 8 + hh) * 128 + d) * 16 + kk]);
}

// -------- generic batched transpose to bf16: dst[b][c][r] = src[b][r][c] --------
__global__ __launch_bounds__(256) void tr_bf16_kernel(const float* __restrict__ src,
                                                      ushort_t* __restrict__ dst,
                                                      int R, int C, int total) {
    int idx = blockIdx.x * 256 + threadIdx.x;
    if (idx >= total) return;
    int b = idx / (R * C);
    int rem = idx - b * (R * C);
    int r = rem / C, c = rem - r * C;
    dst[(size_t)b * R * C + (size_t)c * R + r] = f2bf(src[idx]);
}

// ---------------- embed: h = relu(x @ We), write fp32 + bf16 ----------------
__global__ __launch_bounds__(256) void embed_kernel(const float* __restrict__ x,
                                                    const float* __restrict__ We,
                                                    float* __restrict__ hf,
                                                    ushort_t* __restrict__ hb) {
    const int t = threadIdx.x;
    const int d = t & 127;
    const int m = blockIdx.x * 2 + (t >> 7);
    const float* xr = x + (size_t)m * 16;
    float acc = 0.f;
#pragma unroll
    for (int k = 0; k < 16; k++) acc += xr[k] * We[k * 128 + d];
    acc = fmaxf(acc, 0.f);
    hf[(size_t)m * 128 + d] = acc;
    hb[(size_t)m * 128 + d] = f2bf(acc);
}

// ---------------- bf16 MFMA GEMM (m97-style): C = [relu](A @ Bt^T [+bias] [+Cin]) ----------------
template <int BM, bool RELU, bool BIAS, bool RES, bool WF32, bool WB16>
__global__ __launch_bounds__(256) void gemm_bt(const ushort_t* __restrict__ A,
                                               const ushort_t* __restrict__ Bt,
                                               const float* __restrict__ bias,
                                               const float* __restrict__ Cin,
                                               float* __restrict__ Cf,
                                               ushort_t* __restrict__ Cb,
                                               int M, int N, int K) {
    constexpr int NJ = (BM == 128) ? 4 : 2;
    __shared__ __align__(16) ushort_t Asm[BM * 32];
    __shared__ __align__(16) ushort_t Bsm[128 * 32];
    const int tid = threadIdx.x;
    const int w = tid >> 6, l = tid & 63;
    const int m0 = blockIdx.y * BM, n0 = blockIdx.x * 128;
    const int WM = (BM == 128) ? (w & 1) * 64 : 0;
    const int WN = (BM == 128) ? (w >> 1) * 64 : w * 32;
    const int lr = l & 15, lq = l >> 4;
    const int sar = w * 16 + (l >> 2);
    const int sac = (l & 3) * 8;

    f32x4 acc[4][NJ];
#pragma unroll
    for (int i = 0; i < 4; i++)
#pragma unroll
        for (int j = 0; j < NJ; j++) acc[i][j] = (f32x4){0.f, 0.f, 0.f, 0.f};

    for (int k0 = 0; k0 < K; k0 += 32) {
#pragma unroll
        for (int it = 0; it < BM / 64; it++)
            gload16(A + (size_t)(m0 + it * 64 + sar) * K + k0 + sac,
                    &Asm[(it * 64 + sar) * 32 + sac]);
#pragma unroll
        for (int it = 0; it < 2; it++)
            gload16(Bt + (size_t)(n0 + it * 64 + sar) * K + k0 + sac,
                    &Bsm[(it * 64 + sar) * 32 + sac]);
        __syncthreads();
        short8 af[4], bfr[NJ];
#pragma unroll
        for (int i = 0; i < 4; i++)
            af[i] = *(const short8*)&Asm[(WM + i * 16 + lr) * 32 + lq * 8];
#pragma unroll
        for (int j = 0; j < NJ; j++)
            bfr[j] = *(const short8*)&Bsm[(WN + j * 16 + lr) * 32 + lq * 8];
#pragma unroll
        for (int i = 0; i < 4; i++)
#pragma unroll
            for (int j = 0; j < NJ; j++)
                acc[i][j] = __builtin_amdgcn_mfma_f32_16x16x32_bf16(af[i], bfr[j], acc[i][j], 0, 0, 0);
        __syncthreads();
    }

    float bv[NJ];
#pragma unroll
    for (int j = 0; j < NJ; j++) {
        const int n = n0 + WN + j * 16 + lr;
        bv[j] = BIAS ? bias[n] : 0.f;
    }
#pragma unroll
    for (int i = 0; i < 4; i++) {
#pragma unroll
        for (int r = 0; r < 4; r++) {
            const int m = m0 + WM + i * 16 + lq * 4 + r;
#pragma unroll
            for (int j = 0; j < NJ; j++) {
                const int n = n0 + WN + j * 16 + lr;
                float v = acc[i][j][r] + bv[j];
                if (RES) v += Cin[(size_t)m * N + n];
                if (RELU) v = fmaxf(v, 0.f);
                if (WF32) Cf[(size_t)m * N + n] = v;
                if (WB16) Cb[(size_t)m * N + n] = f2bf(v);
            }
        }
    }
}

// ---------------- MFMA flash attention ----------------
// qkv bf16 [16384][384]: q=h*16+k, k=128+h*16+k, v=256+h*16+k.
// Block = (b, h, half): 512 blocks, 256 threads = 4 waves, wave owns 4 q-tiles of 16.
// S = Q K^T via mfma_16x16x32 (K padded to 32 with zero row on B side),
// masked softmax in registers (unnormalized), P->LDS bf16, PV via mfma, O normalized at end.
__global__ __launch_bounds__(256) void attn_mfma_kernel(const ushort_t* __restrict__ qkv,
                                                        const uint_t* __restrict__ pm,
                                                        ushort_t* __restrict__ Aout) {
    __shared__ __align__(16) ushort_t KsA[512 * 8];   // k 0..7  per key row
    __shared__ __align__(16) ushort_t KsB[512 * 8];   // k 8..15 per key row
    __shared__ __align__(16) ushort_t Zrow[8];        // zeros (k 16..31)
    __shared__ __align__(16) ushort_t Vt[16 * 520];   // V^T [dv][n], pad to 520
    __shared__ __align__(16) uint_t   Msk[4][256];    // per-wave q-tile mask words
    __shared__ __align__(16) ushort_t Ps[4][16 * 136];// per-wave P chunk [16 q][128 nk], stride 136

    const int tid = threadIdx.x;
    const int w = tid >> 6, l = tid & 63;
    const int lr = l & 15, lq = l >> 4;
    const int bx = blockIdx.x;
    const int b = bx >> 4;
    const int h = (bx >> 1) & 7;
    const int half = bx & 1;
    const size_t base = (size_t)b * 512 * 384;

    if (tid < 4) ((uint_t*)Zrow)[tid] = 0u;

    // stage K halves via global_load_lds (dest = base + lane*16, contiguous)
#pragma unroll
    for (int i = 0; i < 2; i++) {
        const int row = (i * 4 + w) * 64 + l;
        const ushort_t* g = qkv + base + (size_t)row * 384 + 128 + h * 16;
        gload16(g, &KsA[row * 8]);
        gload16(g + 8, &KsB[row * 8]);
    }
    // stage V transposed (scalar LDS writes, one-time)
#pragma unroll
    for (int i = 0; i < 2; i++) {
        const int row = i * 256 + tid;
        const ushort_t* g = qkv + base + (size_t)row * 384 + 256 + h * 16;
        uint4 v0 = *(const uint4*)g;
        uint4 v1 = *(const uint4*)(g + 8);
        ushort_t tmp[16];
        *(uint4*)tmp = v0;
        *(uint4*)(tmp + 8) = v1;
#pragma unroll
        for (int d = 0; d < 16; d++) Vt[d * 520 + row] = tmp[d];
    }
    __syncthreads();

    const ushort_t* kbase = (lq == 0) ? KsA : (lq == 1) ? KsB : Zrow;
    const ushort_t* kptr = (lq < 2) ? (kbase + lr * 8) : kbase;
    const int kstep = (lq < 2) ? 128 : 0;              // ushorts per j-tile (16 rows * 8)
    const uint_t blo = 1u << lr, bhi = blo << 16;

    for (int qt = 0; qt < 4; qt++) {
        const int qr0 = half * 256 + w * 64 + qt * 16;
        // stage this q-tile's mask words (1 KiB contiguous)
        gload16(pm + ((size_t)(b * 512 + qr0) * 16) + l * 4, &Msk[w][l * 4]);
        // Q a-frag direct from global (lq>=2 lanes read junk; B side is zero there)
        short8 af = *(const short8*)(qkv + base + (size_t)(qr0 + lr) * 384 + h * 16 + lq * 8);

        f32x4 acc[32];
#pragma unroll
        for (int j = 0; j < 32; j++) acc[j] = (f32x4){0.f, 0.f, 0.f, 0.f};
#pragma unroll
        for (int j = 0; j < 32; j++) {
            short8 bfr = *(const short8*)(kptr + j * kstep);
            acc[j] = __builtin_amdgcn_mfma_f32_16x16x32_bf16(af, bfr, acc[j], 0, 0, 0);
        }
        __asm__ volatile("s_waitcnt vmcnt(0)" ::: "memory");   // Msk staged

        // mask apply + row max (row = lq*4+r, col = j*16+lr)
        float mrow[4] = {-1e30f, -1e30f, -1e30f, -1e30f};
#pragma unroll
        for (int jb = 0; jb < 4; jb++) {
#pragma unroll
            for (int r = 0; r < 4; r++) {
                uint4 mw = *(const uint4*)&Msk[w][(lq * 4 + r) * 16 + jb * 4];
                const uint_t w0 = mw.x, w1 = mw.y, w2 = mw.z, w3 = mw.w;
#pragma unroll
                for (int jj = 0; jj < 8; jj++) {
                    const int j = jb * 8 + jj;
                    const uint_t word = (jj >> 1) == 0 ? w0 : (jj >> 1) == 1 ? w1
                                        : (jj >> 1) == 2 ? w2 : w3;
                    const uint_t bit = word & ((jj & 1) ? bhi : blo);
                    const float sv = bit ? acc[j][r] : -1e30f;
                    acc[j][r] = sv;
                    mrow[r] = fmaxf(mrow[r], sv);
                }
            }
        }
        // softmax (unnormalized): p = exp(0.25*(s - m)); row sum
        float lsum[4];
#pragma unroll
        for (int r = 0; r < 4; r++) {
#pragma unroll
            for (int o = 1; o < 16; o <<= 1) mrow[r] = fmaxf(mrow[r], __shfl_xor(mrow[r], o, 16));
            const float c2 = -mrow[r] * 0.25f;
            float s0 = 0.f;
#pragma unroll
            for (int j = 0; j < 32; j++) {
                const float p = __expf(__builtin_fmaf(acc[j][r], 0.25f, c2));
                acc[j][r] = p;
                s0 += p;
            }
#pragma unroll
            for (int o = 1; o < 16; o <<= 1) s0 += __shfl_xor(s0, o, 16);
            lsum[r] = s0;
        }
        float inv_[4];
#pragma unroll
        for (int r = 0; r < 4; r++) inv_[r] = 1.0f / lsum[r];

        // PV in 4 chunks of 128 keys: P -> LDS bf16, then 4 mfma per chunk
        f32x4 oacc = (f32x4){0.f, 0.f, 0.f, 0.f};
#pragma unroll
        for (int c = 0; c < 4; c++) {
#pragma unroll
            for (int jj = 0; jj < 8; jj++) {
#pragma unroll
                for (int r = 0; r < 4; r++) {
                    union { float f; uint_t u; } pu;
                    pu.f = acc[c * 8 + jj][r];
                    Ps[w][(lq * 4 + r) * 136 + jj * 16 + lr] = (ushort_t)((pu.u + 0x8000u) >> 16);
                }
            }
#pragma unroll
            for (int kt = 0; kt < 4; kt++) {
                short8 pa = *(const short8*)&Ps[w][lr * 136 + kt * 32 + lq * 8];
                short8 vb = *(const short8*)&Vt[lr * 520 + c * 128 + kt * 32 + lq * 8];
                oacc = __builtin_amdgcn_mfma_f32_16x16x32_bf16(pa, vb, oacc, 0, 0, 0);
            }
        }
        // O: lane holds q = lq*4+r, dv = lr
#pragma unroll
        for (int r = 0; r < 4; r++) {
            const float ov = oacc[r] * inv_[r];
            Aout[(size_t)(b * 512 + qr0 + lq * 4 + r) * 128 + h * 16 + lr] = f2bf(ov);
        }
    }
}

// ------------- pooled readout part -------------
__global__ __launch_bounds__(128) void pool_kernel(const float* __restrict__ h,
                                                   const float* __restrict__ Wp,
                                                   const float* __restrict__ Wr,
                                                   const float* __restrict__ br,
                                                   float* __restrict__ pb) {
    const int b = blockIdx.x, t = threadIdx.x;
    __shared__ float pooled[128];
    __shared__ float rp[128];
    float acc = 0.f;
    const float* hb = h + (size_t)b * N_SEQ * D_EMB;
    for (int n = 0; n < N_SEQ; n++) acc += hb[n * D_EMB + t];
    pooled[t] = acc * (1.0f / N_SEQ);
    __syncthreads();
    float acc2 = 0.f;
    for (int d = 0; d < D_EMB; d++) acc2 += pooled[d] * Wp[d * D_EMB + t];
    rp[t] = fmaxf(acc2, 0.f);
    __syncthreads();
    if (t < OUT_DIM) {
        float a = br[t];
        for (int j = 0; j < D_EMB; j++) a += rp[j] * Wr[j * OUT_DIM + t];
        pb[b * OUT_DIM + t] = a;
    }
}

// ------------- final readout -------------
__global__ __launch_bounds__(128) void out_kernel(const float* __restrict__ h,
                                                  const float* __restrict__ Wr,
                                                  const float* __restrict__ pb,
                                                  float* __restrict__ out) {
    const int row = blockIdx.x, tid = threadIdx.x;
    __shared__ float rp[128];
    rp[tid] = fmaxf(h[(size_t)row * D_EMB + tid], 0.f);
    __syncthreads();
    if (tid < 96) {
        const int o = tid >> 5, j0 = tid & 31;
        float acc = 0.f;
        for (int j = j0; j < 128; j += 32) acc += rp[j] * Wr[(128 + j) * OUT_DIM + o];
        for (int off = 16; off; off >>= 1) acc += __shfl_down(acc, off, 32);
        if (j0 == 0) out[(size_t)row * OUT_DIM + o] = acc + pb[(row >> 9) * OUT_DIM + o];
    }
}

extern "C" void kernel_launch(void* const* d_in, const int* in_sizes, int n_in,
                              void* d_out, int out_size, void* d_ws, size_t ws_size,
                              hipStream_t stream) {
    const float* x    = (const float*)d_in[0];
    const int*   mask = (const int*)d_in[1];
    const float* We   = (const float*)d_in[2];
    const float* Wq   = (const float*)d_in[3];
    const float* Wk   = (const float*)d_in[4];
    const float* Wv   = (const float*)d_in[5];
    const float* Wout = (const float*)d_in[6];
    const float* Wff1 = (const float*)d_in[7];
    const float* bff1 = (const float*)d_in[8];
    const float* Wff2 = (const float*)d_in[9];
    const float* bff2 = (const float*)d_in[10];
    const float* Wp   = (const float*)d_in[11];
    const float* Wr   = (const float*)d_in[12];
    const float* br   = (const float*)d_in[13];
    float* out = (float*)d_out;

    char* ws = (char*)d_ws;
    unsigned long long* pm64 = (unsigned long long*)(ws + 0);        // 1 MiB
    const uint_t* pm32       = (const uint_t*)(ws + 0);
    ushort_t* wqkvT = (ushort_t*)(ws + 1048576);                     // 288 KiB
    ushort_t* woutT = (ushort_t*)(ws + 1343488);                     // 96 KiB
    ushort_t* wff1T = (ushort_t*)(ws + 1441792);                     // 384 KiB
    ushort_t* wff2T = (ushort_t*)(ws + 1835008);                     // 384 KiB
    float*    pbbuf = (float*)(ws + 2228224);                        // 384 B
    float*    hbuf  = (float*)(ws + 4194304);                        // 8 MiB fp32 residual
    ushort_t* hb16  = (ushort_t*)(ws + 12582912);                    // 4 MiB bf16 mirror of h
    ushort_t* qkv16 = (ushort_t*)(ws + 16777216);                    // 12 MiB bf16 QKV
    ushort_t* t16   = (ushort_t*)(ws + 16777216);                    // 16 MiB bf16 FFN mid (aliases qkv16)
    ushort_t* a16   = (ushort_t*)(ws + 41943040);                    // 4 MiB bf16 attn out

    pack_mask_kernel<<<(B_BATCH * N_SEQ * N_SEQ) / 256, 256, 0, stream>>>(mask, pm64);
    repack_qkv_bt_kernel<<<576, 256, 0, stream>>>(Wq, Wk, Wv, wqkvT);
    tr_bf16_kernel<<<192, 256, 0, stream>>>(Wout, woutT, 128, 128, 3 * 128 * 128);
    tr_bf16_kernel<<<768, 256, 0, stream>>>(Wff1, wff1T, 128, 512, 3 * 128 * 512);
    tr_bf16_kernel<<<768, 256, 0, stream>>>(Wff2, wff2T, 512, 128, 3 * 512 * 128);

    embed_kernel<<<M_ROWS / 2, 256, 0, stream>>>(x, We, hbuf, hb16);

    for (int l = 0; l < L_LAYERS; l++) {
        // QKV: bf16 out only
        gemm_bt<128, false, false, false, false, true><<<dim3(3, M_ROWS / 128), 256, 0, stream>>>(
            hb16, wqkvT + (size_t)l * 384 * 128, nullptr, nullptr, nullptr, qkv16,
            M_ROWS, 384, 128);
        // MFMA flash attention -> a16 bf16
        attn_mfma_kernel<<<512, 256, 0, stream>>>(qkv16, pm32, a16);
        // h += a16 @ Wout
        gemm_bt<64, false, false, true, true, true><<<dim3(1, M_ROWS / 64), 256, 0, stream>>>(
            a16, woutT + (size_t)l * 128 * 128, nullptr, hbuf, hbuf, hb16,
            M_ROWS, 128, 128);
        // t = relu(h @ Wff1 + bff1)
        gemm_bt<128, true, true, false, false, true><<<dim3(4, M_ROWS / 128), 256, 0, stream>>>(
            hb16, wff1T + (size_t)l * 512 * 128, bff1 + l * 512, nullptr, nullptr, t16,
            M_ROWS, 512, 128);
        // h += t16 @ Wff2 + bff2
        gemm_bt<64, false, true, true, true, true><<<dim3(1, M_ROWS / 64), 256, 0, stream>>>(
            t16, wff2T + (size_t)l * 128 * 512, bff2 + l * 128, hbuf, hbuf, hb16,
            M_ROWS, 128, 512);
    }

    pool_kernel<<<B_BATCH, 128, 0, stream>>>(hbuf, Wp, Wr, br, pbbuf);
    out_kernel<<<M_ROWS, 128, 0, stream>>>(hbuf, Wr, pbbuf, out);
}